// Round 1
// baseline (600.461 us; speedup 1.0000x reference)
//
#include <hip/hip_runtime.h>
#include <cstdint>
#include <cstddef>

typedef __bf16 bf16x8 __attribute__((ext_vector_type(8)));
typedef float f32x4 __attribute__((ext_vector_type(4)));
typedef unsigned short u16x4 __attribute__((ext_vector_type(4)));

// fp32 -> bf16 round-to-nearest-even (no NaN inputs expected)
__device__ __forceinline__ unsigned short f2bf(float f) {
  union { float f; unsigned u; } v; v.f = f;
  unsigned r = (v.u + 0x7FFF + ((v.u >> 16) & 1)) >> 16;
  return (unsigned short)r;
}

// async global->LDS, 16B per lane; LDS dest = wave-uniform base + lane*16
__device__ __forceinline__ void gl2lds16(const void* g, void* l) {
  __builtin_amdgcn_global_load_lds(
      (const __attribute__((address_space(1))) void*)g,
      (__attribute__((address_space(3))) void*)l,
      16, 0, 0);
}

// ---------------------------------------------------------------- prep
__global__ __launch_bounds__(256) void cast_f32_bf16(
    const float* __restrict__ in, unsigned short* __restrict__ out, int n) {
  int i = (blockIdx.x * 256 + threadIdx.x) * 4;
  if (i >= n) return;
  float4 v = *(const float4*)(in + i);
  u16x4 o;
  o[0] = f2bf(v.x); o[1] = f2bf(v.y); o[2] = f2bf(v.z); o[3] = f2bf(v.w);
  *(u16x4*)(out + i) = o;
}

// out[c][r] = bf16(in[r][c]); in is [R][C] fp32 row-major
__global__ __launch_bounds__(256) void transpose_cast(
    const float* __restrict__ in, unsigned short* __restrict__ out, int R, int C) {
  __shared__ float t[32][33];
  int c0 = blockIdx.x * 32, r0 = blockIdx.y * 32;
  int tx = threadIdx.x, ty = threadIdx.y;
#pragma unroll
  for (int j = 0; j < 4; ++j)
    t[ty + j * 8][tx] = in[(size_t)(r0 + ty + j * 8) * C + c0 + tx];
  __syncthreads();
#pragma unroll
  for (int j = 0; j < 4; ++j)
    out[(size_t)(c0 + ty + j * 8) * R + r0 + tx] = f2bf(t[tx][ty + j * 8]);
}

// ---------------------------------------------------------------- GEMM (C = A[M,K] * B[N,K]^T)
// EPI 0: scatter to Q/K/Vt bf16 head-major (+bias). EPI 1: fp32 out (+bias).
template <int EPI>
__global__ __launch_bounds__(256) void gemm_bt(
    const unsigned short* __restrict__ A, const unsigned short* __restrict__ Bm,
    const float* __restrict__ bias, float* __restrict__ outF,
    unsigned short* __restrict__ Qb, unsigned short* __restrict__ Kb,
    unsigned short* __restrict__ Vt, int M, int N, int K) {
  __shared__ unsigned short As[128 * 32];
  __shared__ unsigned short Bs[128 * 32];
  const int tid = threadIdx.x;
  const int bm = blockIdx.x * 128;
  const int bn = blockIdx.y * 128;
  const int wave = tid >> 6, lane = tid & 63;
  const int wm = (wave >> 1) * 64, wn = (wave & 1) * 64;
  const int lr = lane & 15, lq = lane >> 4;

  f32x4 acc[4][4] = {};

  const int c0 = tid, c1 = tid + 256;
  const int rA0 = c0 >> 2, colA0 = (c0 & 3) * 8;
  const int rA1 = c1 >> 2, colA1 = (c1 & 3) * 8;

  for (int k0 = 0; k0 < K; k0 += 32) {
    __syncthreads();
    gl2lds16(A + (size_t)(bm + rA0) * K + k0 + colA0, As + c0 * 8);
    gl2lds16(A + (size_t)(bm + rA1) * K + k0 + colA1, As + c1 * 8);
    gl2lds16(Bm + (size_t)(bn + rA0) * K + k0 + colA0, Bs + c0 * 8);
    gl2lds16(Bm + (size_t)(bn + rA1) * K + k0 + colA1, Bs + c1 * 8);
    __syncthreads();
    bf16x8 af[4], bfr[4];
#pragma unroll
    for (int mi = 0; mi < 4; ++mi)
      af[mi] = *(const bf16x8*)(As + (wm + mi * 16 + lr) * 32 + lq * 8);
#pragma unroll
    for (int nj = 0; nj < 4; ++nj)
      bfr[nj] = *(const bf16x8*)(Bs + (wn + nj * 16 + lr) * 32 + lq * 8);
#pragma unroll
    for (int mi = 0; mi < 4; ++mi)
#pragma unroll
      for (int nj = 0; nj < 4; ++nj)
        acc[mi][nj] = __builtin_amdgcn_mfma_f32_16x16x32_bf16(af[mi], bfr[nj], acc[mi][nj], 0, 0, 0);
  }

#pragma unroll
  for (int mi = 0; mi < 4; ++mi) {
#pragma unroll
    for (int nj = 0; nj < 4; ++nj) {
#pragma unroll
      for (int r = 0; r < 4; ++r) {
        int m = bm + wm + mi * 16 + lq * 4 + r;  // C layout: row=(lane>>4)*4+reg
        int n = bn + wn + nj * 16 + lr;          //           col=lane&15
        float v = acc[mi][nj][r] + bias[n];
        if (EPI == 0) {
          int b = m >> 11, t = m & 2047;
          int part = n >> 10, d = n & 1023;
          int h = d >> 6, hd = d & 63;
          unsigned short bv = f2bf(v);
          size_t qk = ((size_t)(b * 16 + h) * 2048 + t) * 64 + hd;
          if (part == 0)      Qb[qk] = bv;
          else if (part == 1) Kb[qk] = bv;
          else                Vt[((size_t)(b * 16 + h) * 64 + hd) * 2048 + t] = bv;
        } else {
          outF[(size_t)m * N + n] = v;
        }
      }
    }
  }
}

// ---------------------------------------------------------------- flash attention
// block = (b, h, 128-row q-tile); 4 independent waves of 32 q-rows (no barriers).
__global__ __launch_bounds__(256) void flash_attn(
    const unsigned short* __restrict__ Qb, const unsigned short* __restrict__ Kb,
    const unsigned short* __restrict__ Vt, const int* __restrict__ mask,
    unsigned short* __restrict__ ctx) {
  __shared__ unsigned short Pl[4][32 * 72];  // stride 72: 16B-aligned rows, low conflict
  const int bid = blockIdx.x;
  const int qt = bid & 15;
  const int bh = bid >> 4;
  const int b = bh >> 4, h = bh & 15;
  const int wave = threadIdx.x >> 6, lane = threadIdx.x & 63;
  const int lr = lane & 15, lq = lane >> 4;
  const int q0 = qt * 128 + wave * 32;

  const unsigned short* Qh = Qb + (size_t)bh * 2048 * 64;
  const unsigned short* Kh = Kb + (size_t)bh * 2048 * 64;
  const unsigned short* Vh = Vt + (size_t)bh * 64 * 2048;
  const int* mb = mask + b * 2048;

  // Q A-frags in registers for the whole kernel: A[m=lane&15][k=quad*8+j]
  bf16x8 qf[2][2];
#pragma unroll
  for (int mi = 0; mi < 2; ++mi)
#pragma unroll
    for (int kk = 0; kk < 2; ++kk)
      qf[mi][kk] = *(const bf16x8*)(Qh + (size_t)(q0 + mi * 16 + lr) * 64 + kk * 32 + lq * 8);

  f32x4 O[2][4] = {};
  float mrow[2][4], lrow[2][4];
#pragma unroll
  for (int mi = 0; mi < 2; ++mi)
#pragma unroll
    for (int r = 0; r < 4; ++r) { mrow[mi][r] = -1e30f; lrow[mi][r] = 0.f; }

  unsigned short* Pw = Pl[wave];
  const int kend = q0 + 32;  // causal: this wave's max row is q0+31
  for (int kc = 0; kc < kend; kc += 64) {
    // S = Q K^T   (B-operand = K rows, contraction = hd, contiguous)
    f32x4 S[2][4] = {};
#pragma unroll
    for (int nj = 0; nj < 4; ++nj) {
      bf16x8 kf0 = *(const bf16x8*)(Kh + (size_t)(kc + nj * 16 + lr) * 64 + lq * 8);
      bf16x8 kf1 = *(const bf16x8*)(Kh + (size_t)(kc + nj * 16 + lr) * 64 + 32 + lq * 8);
#pragma unroll
      for (int mi = 0; mi < 2; ++mi) {
        S[mi][nj] = __builtin_amdgcn_mfma_f32_16x16x32_bf16(qf[mi][0], kf0, S[mi][nj], 0, 0, 0);
        S[mi][nj] = __builtin_amdgcn_mfma_f32_16x16x32_bf16(qf[mi][1], kf1, S[mi][nj], 0, 0, 0);
      }
    }
    int keyv[4], padv[4];
#pragma unroll
    for (int nj = 0; nj < 4; ++nj) {
      keyv[nj] = kc + nj * 16 + lr;
      padv[nj] = mb[keyv[nj]];
    }
    // online softmax per q-row; row lives in 16-lane group (lane&15 = key col)
#pragma unroll
    for (int mi = 0; mi < 2; ++mi) {
#pragma unroll
      for (int r = 0; r < 4; ++r) {
        const int q = q0 + mi * 16 + lq * 4 + r;
        float sv[4];
#pragma unroll
        for (int nj = 0; nj < 4; ++nj) {
          float s = S[mi][nj][r] * 0.125f;  // 1/sqrt(64)
          sv[nj] = (keyv[nj] > q || padv[nj]) ? -1e30f : s;
        }
        float mx = fmaxf(fmaxf(sv[0], sv[1]), fmaxf(sv[2], sv[3]));
        mx = fmaxf(mx, __shfl_xor(mx, 1, 16));
        mx = fmaxf(mx, __shfl_xor(mx, 2, 16));
        mx = fmaxf(mx, __shfl_xor(mx, 4, 16));
        mx = fmaxf(mx, __shfl_xor(mx, 8, 16));
        const float mold = mrow[mi][r];
        const float mnew = fmaxf(mold, mx);
        const float alpha = __expf(mold - mnew);
        mrow[mi][r] = mnew;
        float rs = 0.f;
#pragma unroll
        for (int nj = 0; nj < 4; ++nj) {
          float p = __expf(sv[nj] - mnew);
          S[mi][nj][r] = p;
          rs += p;
        }
        rs += __shfl_xor(rs, 1, 16);
        rs += __shfl_xor(rs, 2, 16);
        rs += __shfl_xor(rs, 4, 16);
        rs += __shfl_xor(rs, 8, 16);
        lrow[mi][r] = lrow[mi][r] * alpha + rs;
#pragma unroll
        for (int nj = 0; nj < 4; ++nj) O[mi][nj][r] *= alpha;
      }
    }
    // P: C-layout -> LDS -> A-layout (per-wave slab, no cross-wave sharing)
#pragma unroll
    for (int mi = 0; mi < 2; ++mi)
#pragma unroll
      for (int r = 0; r < 4; ++r)
#pragma unroll
        for (int nj = 0; nj < 4; ++nj)
          Pw[(mi * 16 + lq * 4 + r) * 72 + nj * 16 + lr] = f2bf(S[mi][nj][r]);
    __threadfence_block();
    bf16x8 pf[2][2];
#pragma unroll
    for (int mi = 0; mi < 2; ++mi)
#pragma unroll
      for (int kk = 0; kk < 2; ++kk)
        pf[mi][kk] = *(const bf16x8*)(Pw + (mi * 16 + lr) * 72 + kk * 32 + lq * 8);
    // O += P * V  (B-operand = Vt rows [hd][t], contraction = key, contiguous)
#pragma unroll
    for (int nj = 0; nj < 4; ++nj) {
      bf16x8 vf0 = *(const bf16x8*)(Vh + (size_t)(nj * 16 + lr) * 2048 + kc + lq * 8);
      bf16x8 vf1 = *(const bf16x8*)(Vh + (size_t)(nj * 16 + lr) * 2048 + kc + 32 + lq * 8);
#pragma unroll
      for (int mi = 0; mi < 2; ++mi) {
        O[mi][nj] = __builtin_amdgcn_mfma_f32_16x16x32_bf16(pf[mi][0], vf0, O[mi][nj], 0, 0, 0);
        O[mi][nj] = __builtin_amdgcn_mfma_f32_16x16x32_bf16(pf[mi][1], vf1, O[mi][nj], 0, 0, 0);
      }
    }
  }
  // epilogue: ctx[b][t][h*64+hd] bf16
#pragma unroll
  for (int mi = 0; mi < 2; ++mi) {
#pragma unroll
    for (int r = 0; r < 4; ++r) {
      float inv = 1.0f / lrow[mi][r];
      int q = q0 + mi * 16 + lq * 4 + r;
#pragma unroll
      for (int nj = 0; nj < 4; ++nj)
        ctx[((size_t)b * 2048 + q) * 1024 + h * 64 + nj * 16 + lr] = f2bf(O[mi][nj][r] * inv);
    }
  }
}

// ---------------------------------------------------------------- launch
extern "C" void kernel_launch(void* const* d_in, const int* in_sizes, int n_in,
                              void* d_out, int out_size, void* d_ws, size_t ws_size,
                              hipStream_t stream) {
  const float* x    = (const float*)d_in[0];
  const float* Wqkv = (const float*)d_in[1];
  const float* bqkv = (const float*)d_in[2];
  const float* Wo   = (const float*)d_in[3];
  const float* bo   = (const float*)d_in[4];
  const int*   mask = (const int*)d_in[5];
  float* out = (float*)d_out;

  unsigned short* ws = (unsigned short*)d_ws;
  const size_t SZ_X = (size_t)8192 * 1024;  // B*T*D
  unsigned short* xb    = ws;                                   // 16 MB, reused as ctx
  unsigned short* WqkvT = xb + SZ_X;                            // 6 MB
  unsigned short* WoT   = WqkvT + (size_t)3072 * 1024;          // 2 MB
  unsigned short* Qb    = WoT + (size_t)1024 * 1024;            // 16 MB
  unsigned short* Kb    = Qb + SZ_X;                            // 16 MB
  unsigned short* Vt    = Kb + SZ_X;                            // 16 MB
  unsigned short* ctx   = xb;  // xb dead after GEMM1

  cast_f32_bf16<<<8192, 256, 0, stream>>>(x, xb, (int)SZ_X);
  transpose_cast<<<dim3(96, 32), dim3(32, 8), 0, stream>>>(Wqkv, WqkvT, 1024, 3072);
  transpose_cast<<<dim3(32, 32), dim3(32, 8), 0, stream>>>(Wo, WoT, 1024, 1024);
  gemm_bt<0><<<dim3(64, 24), 256, 0, stream>>>(xb, WqkvT, bqkv, nullptr, Qb, Kb, Vt,
                                               8192, 3072, 1024);
  flash_attn<<<1024, 256, 0, stream>>>(Qb, Kb, Vt, mask, ctx);
  gemm_bt<1><<<dim3(64, 8), 256, 0, stream>>>(ctx, WoT, bo, out, nullptr, nullptr, nullptr,
                                              8192, 1024, 1024);
}

// Round 2
// 415.529 us; speedup vs baseline: 1.4451x; 1.4451x over previous
//
#include <hip/hip_runtime.h>
#include <cstdint>
#include <cstddef>

typedef __bf16 bf16x8 __attribute__((ext_vector_type(8)));
typedef __bf16 bf16x4 __attribute__((ext_vector_type(4)));
typedef float f32x4 __attribute__((ext_vector_type(4)));
typedef unsigned short u16x4 __attribute__((ext_vector_type(4)));
typedef short s16x4 __attribute__((ext_vector_type(4)));

// fp32 -> bf16 round-to-nearest-even
__device__ __forceinline__ unsigned short f2bf(float f) {
  union { float f; unsigned u; } v; v.f = f;
  unsigned r = (v.u + 0x7FFF + ((v.u >> 16) & 1)) >> 16;
  return (unsigned short)r;
}

// async global->LDS, 16B per lane
__device__ __forceinline__ void gl2lds16(const void* g, void* l) {
  __builtin_amdgcn_global_load_lds(
      (const __attribute__((address_space(1))) void*)g,
      (__attribute__((address_space(3))) void*)l,
      16, 0, 0);
}

// ---------------------------------------------------------------- prep
__global__ __launch_bounds__(256) void cast_f32_bf16(
    const float* __restrict__ in, unsigned short* __restrict__ out, int n) {
  int i = (blockIdx.x * 256 + threadIdx.x) * 4;
  if (i >= n) return;
  float4 v = *(const float4*)(in + i);
  u16x4 o;
  o[0] = f2bf(v.x); o[1] = f2bf(v.y); o[2] = f2bf(v.z); o[3] = f2bf(v.w);
  *(u16x4*)(out + i) = o;
}

__global__ __launch_bounds__(256) void transpose_cast(
    const float* __restrict__ in, unsigned short* __restrict__ out, int R, int C) {
  __shared__ float t[32][33];
  int c0 = blockIdx.x * 32, r0 = blockIdx.y * 32;
  int tx = threadIdx.x, ty = threadIdx.y;
#pragma unroll
  for (int j = 0; j < 4; ++j)
    t[ty + j * 8][tx] = in[(size_t)(r0 + ty + j * 8) * C + c0 + tx];
  __syncthreads();
#pragma unroll
  for (int j = 0; j < 4; ++j)
    out[(size_t)(c0 + ty + j * 8) * R + r0 + tx] = f2bf(t[tx][ty + j * 8]);
}

// key_padding_mask (int 0/1) -> additive float (-1e30 where masked)
__global__ __launch_bounds__(256) void prep_pad(
    const int* __restrict__ mask, float* __restrict__ padd, int n) {
  int i = blockIdx.x * 256 + threadIdx.x;
  if (i < n) padd[i] = mask[i] ? -1e30f : 0.0f;
}

// ---------------------------------------------------------------- GEMM (C = A[M,K] * B[N,K]^T)
template <int EPI>
__global__ __launch_bounds__(256) void gemm_bt(
    const unsigned short* __restrict__ A, const unsigned short* __restrict__ Bm,
    const float* __restrict__ bias, float* __restrict__ outF,
    unsigned short* __restrict__ Qb, unsigned short* __restrict__ Kb,
    unsigned short* __restrict__ Vt, int M, int N, int K) {
  __shared__ unsigned short As[128 * 32];
  __shared__ unsigned short Bs[128 * 32];
  const int tid = threadIdx.x;
  const int bm = blockIdx.x * 128;
  const int bn = blockIdx.y * 128;
  const int wave = tid >> 6, lane = tid & 63;
  const int wm = (wave >> 1) * 64, wn = (wave & 1) * 64;
  const int lr = lane & 15, lq = lane >> 4;

  f32x4 acc[4][4] = {};

  const int c0 = tid, c1 = tid + 256;
  const int rA0 = c0 >> 2, colA0 = (c0 & 3) * 8;
  const int rA1 = c1 >> 2, colA1 = (c1 & 3) * 8;

  for (int k0 = 0; k0 < K; k0 += 32) {
    __syncthreads();
    gl2lds16(A + (size_t)(bm + rA0) * K + k0 + colA0, As + c0 * 8);
    gl2lds16(A + (size_t)(bm + rA1) * K + k0 + colA1, As + c1 * 8);
    gl2lds16(Bm + (size_t)(bn + rA0) * K + k0 + colA0, Bs + c0 * 8);
    gl2lds16(Bm + (size_t)(bn + rA1) * K + k0 + colA1, Bs + c1 * 8);
    __syncthreads();
    bf16x8 af[4], bfr[4];
#pragma unroll
    for (int mi = 0; mi < 4; ++mi)
      af[mi] = *(const bf16x8*)(As + (wm + mi * 16 + lr) * 32 + lq * 8);
#pragma unroll
    for (int nj = 0; nj < 4; ++nj)
      bfr[nj] = *(const bf16x8*)(Bs + (wn + nj * 16 + lr) * 32 + lq * 8);
#pragma unroll
    for (int mi = 0; mi < 4; ++mi)
#pragma unroll
      for (int nj = 0; nj < 4; ++nj)
        acc[mi][nj] = __builtin_amdgcn_mfma_f32_16x16x32_bf16(af[mi], bfr[nj], acc[mi][nj], 0, 0, 0);
  }

#pragma unroll
  for (int mi = 0; mi < 4; ++mi) {
#pragma unroll
    for (int nj = 0; nj < 4; ++nj) {
#pragma unroll
      for (int r = 0; r < 4; ++r) {
        int m = bm + wm + mi * 16 + lq * 4 + r;
        int n = bn + wn + nj * 16 + lr;
        float v = acc[mi][nj][r] + bias[n];
        if (EPI == 0) {
          int b = m >> 11, t = m & 2047;
          int part = n >> 10, d = n & 1023;
          int h = d >> 6, hd = d & 63;
          size_t qk = ((size_t)(b * 16 + h) * 2048 + t) * 64 + hd;
          // fold softmax scale 1/sqrt(64) and log2(e) into Q
          if (part == 0)      Qb[qk] = f2bf(v * 0.18033688011112042f);
          else if (part == 1) Kb[qk] = f2bf(v);
          else                Vt[((size_t)(b * 16 + h) * 64 + hd) * 2048 + t] = f2bf(v);
        } else {
          outF[(size_t)m * N + n] = v;
        }
      }
    }
  }
}

// ---------------------------------------------------------------- flash attention
// S^T = K Q^T so the S C-layout regs (key=4*lq+r, query=lr) directly form the
// A-operand of mfma_16x16x16bf16_1k (k=4*lq+j) for PV — no LDS, no barriers.
template <bool DIAG>
__device__ __forceinline__ void attn_chunk(
    const unsigned short* __restrict__ Kh, const unsigned short* __restrict__ Vh,
    const float* __restrict__ pb, int kc, int q0, int lr, int lq, int bsrc,
    const bf16x8 (&qf)[2][2], f32x4 (&O)[2][4], float (&m)[2], float (&l)[2]) {
  f32x4 S[4][2] = {};
#pragma unroll
  for (int t = 0; t < 4; ++t) {
    const unsigned short* kp = Kh + (size_t)(kc + t * 16 + lr) * 64 + lq * 8;
    bf16x8 kf0 = *(const bf16x8*)(kp);
    bf16x8 kf1 = *(const bf16x8*)(kp + 32);
#pragma unroll
    for (int qt = 0; qt < 2; ++qt) {
      S[t][qt] = __builtin_amdgcn_mfma_f32_16x16x32_bf16(kf0, qf[qt][0], S[t][qt], 0, 0, 0);
      S[t][qt] = __builtin_amdgcn_mfma_f32_16x16x32_bf16(kf1, qf[qt][1], S[t][qt], 0, 0, 0);
    }
  }
  float4 pd[4];
#pragma unroll
  for (int t = 0; t < 4; ++t) pd[t] = *(const float4*)(pb + kc + t * 16 + 4 * lq);

  float alpha_s[2];
#pragma unroll
  for (int qt = 0; qt < 2; ++qt) {
    const int q = q0 + qt * 16 + lr;
#pragma unroll
    for (int t = 0; t < 4; ++t) {
      const float* pdp = (const float*)&pd[t];
#pragma unroll
      for (int r = 0; r < 4; ++r) {
        float s = S[t][qt][r] + pdp[r];
        if (DIAG) {
          int key = kc + t * 16 + 4 * lq + r;
          if (key > q) s = -1e30f;
        }
        S[t][qt][r] = s;
      }
    }
    float mx = -1e30f;
#pragma unroll
    for (int t = 0; t < 4; ++t)
#pragma unroll
      for (int r = 0; r < 4; ++r) mx = fmaxf(mx, S[t][qt][r]);
    mx = fmaxf(mx, __shfl_xor(mx, 16, 64));
    mx = fmaxf(mx, __shfl_xor(mx, 32, 64));
    float mnew = fmaxf(m[qt], mx);
    float al = __builtin_amdgcn_exp2f(m[qt] - mnew);
    m[qt] = mnew;
    float rs = 0.f;
#pragma unroll
    for (int t = 0; t < 4; ++t)
#pragma unroll
      for (int r = 0; r < 4; ++r) {
        float pv = __builtin_amdgcn_exp2f(S[t][qt][r] - mnew);
        S[t][qt][r] = pv;
        rs += pv;
      }
    rs += __shfl_xor(rs, 16, 64);
    rs += __shfl_xor(rs, 32, 64);
    l[qt] = l[qt] * al + rs;
    alpha_s[qt] = al;
  }
  // broadcast alpha from query=lr layout to query=4*lq+r layout, rescale O
#pragma unroll
  for (int qt = 0; qt < 2; ++qt) {
#pragma unroll
    for (int r = 0; r < 4; ++r) {
      float a = __shfl(alpha_s[qt], bsrc + r, 64);
#pragma unroll
      for (int nj = 0; nj < 4; ++nj) O[qt][nj][r] *= a;
    }
  }
  // PV: P regs are already A-frags of 16x16x16 (k = 4*lq + j)
#pragma unroll
  for (int t = 0; t < 4; ++t) {
    s16x4 pf[2];
#pragma unroll
    for (int qt = 0; qt < 2; ++qt) {
      bf16x4 pb4;
#pragma unroll
      for (int r = 0; r < 4; ++r) pb4[r] = (__bf16)S[t][qt][r];
      pf[qt] = __builtin_bit_cast(s16x4, pb4);
    }
#pragma unroll
    for (int nj = 0; nj < 4; ++nj) {
      s16x4 vf = *(const s16x4*)(Vh + (size_t)(nj * 16 + lr) * 2048 + kc + t * 16 + 4 * lq);
#pragma unroll
      for (int qt = 0; qt < 2; ++qt)
        O[qt][nj] = __builtin_amdgcn_mfma_f32_16x16x16bf16_1k(pf[qt], vf, O[qt][nj], 0, 0, 0);
    }
  }
}

__global__ __launch_bounds__(256) void flash_attn(
    const unsigned short* __restrict__ Qb, const unsigned short* __restrict__ Kb,
    const unsigned short* __restrict__ Vt, const float* __restrict__ padd,
    unsigned short* __restrict__ ctx) {
  const int bid = blockIdx.x;
  const int tile = 15 - (bid >> 6);  // longest tiles dispatch first (LPT)
  const int bh = bid & 63;
  const int b = bh >> 4, h = bh & 15;
  const int wave = threadIdx.x >> 6, lane = threadIdx.x & 63;
  const int lr = lane & 15, lq = lane >> 4;
  const int bsrc = 20 * lq;  // shfl src base: lane with lr == 4*lq+r
  const int q0 = tile * 128 + wave * 32;

  const unsigned short* Qh = Qb + (size_t)bh * 2048 * 64;
  const unsigned short* Kh = Kb + (size_t)bh * 2048 * 64;
  const unsigned short* Vh = Vt + (size_t)bh * 64 * 2048;
  const float* pb = padd + b * 2048;

  // Q B-frags persistent in registers (scale pre-folded)
  bf16x8 qf[2][2];
#pragma unroll
  for (int qt = 0; qt < 2; ++qt)
#pragma unroll
    for (int kk = 0; kk < 2; ++kk)
      qf[qt][kk] = *(const bf16x8*)(Qh + (size_t)(q0 + qt * 16 + lr) * 64 + kk * 32 + lq * 8);

  f32x4 O[2][4] = {};
  float m[2] = {-1e30f, -1e30f}, l[2] = {0.f, 0.f};

  const int F = q0 & ~63;  // keys [0,F) need no causal check for this wave
  for (int kc = 0; kc < F; kc += 64)
    attn_chunk<false>(Kh, Vh, pb, kc, q0, lr, lq, bsrc, qf, O, m, l);
  attn_chunk<true>(Kh, Vh, pb, F, q0, lr, lq, bsrc, qf, O, m, l);

#pragma unroll
  for (int qt = 0; qt < 2; ++qt) {
    float linv = 1.0f / l[qt];
#pragma unroll
    for (int r = 0; r < 4; ++r) {
      float li = __shfl(linv, bsrc + r, 64);
      int q = q0 + qt * 16 + 4 * lq + r;
      unsigned short* cp = ctx + ((size_t)b * 2048 + q) * 1024 + h * 64 + lr;
#pragma unroll
      for (int nj = 0; nj < 4; ++nj)
        cp[nj * 16] = f2bf(O[qt][nj][r] * li);
    }
  }
}

// ---------------------------------------------------------------- launch
extern "C" void kernel_launch(void* const* d_in, const int* in_sizes, int n_in,
                              void* d_out, int out_size, void* d_ws, size_t ws_size,
                              hipStream_t stream) {
  const float* x    = (const float*)d_in[0];
  const float* Wqkv = (const float*)d_in[1];
  const float* bqkv = (const float*)d_in[2];
  const float* Wo   = (const float*)d_in[3];
  const float* bo   = (const float*)d_in[4];
  const int*   mask = (const int*)d_in[5];
  float* out = (float*)d_out;

  unsigned short* ws = (unsigned short*)d_ws;
  const size_t SZ_X = (size_t)8192 * 1024;  // B*T*D
  unsigned short* xb    = ws;                                   // 16 MB, reused as ctx
  unsigned short* WqkvT = xb + SZ_X;                            // 6 MB
  unsigned short* WoT   = WqkvT + (size_t)3072 * 1024;          // 2 MB
  unsigned short* Qb    = WoT + (size_t)1024 * 1024;            // 16 MB
  unsigned short* Kb    = Qb + SZ_X;                            // 16 MB
  unsigned short* Vt    = Kb + SZ_X;                            // 16 MB
  float*          padd  = (float*)(Vt + SZ_X);                  // 32 KB
  unsigned short* ctx   = xb;  // xb dead after GEMM1

  cast_f32_bf16<<<8192, 256, 0, stream>>>(x, xb, (int)SZ_X);
  transpose_cast<<<dim3(96, 32), dim3(32, 8), 0, stream>>>(Wqkv, WqkvT, 1024, 3072);
  transpose_cast<<<dim3(32, 32), dim3(32, 8), 0, stream>>>(Wo, WoT, 1024, 1024);
  prep_pad<<<32, 256, 0, stream>>>(mask, padd, 8192);
  gemm_bt<0><<<dim3(64, 24), 256, 0, stream>>>(xb, WqkvT, bqkv, nullptr, Qb, Kb, Vt,
                                               8192, 3072, 1024);
  flash_attn<<<1024, 256, 0, stream>>>(Qb, Kb, Vt, padd, ctx);
  gemm_bt<1><<<dim3(64, 8), 256, 0, stream>>>(ctx, WoT, bo, out, nullptr, nullptr, nullptr,
                                              8192, 1024, 1024);
}